// Round 4
// baseline (250.688 us; speedup 1.0000x reference)
//
#include <hip/hip_runtime.h>
#include <hip/hip_bf16.h>
#include <math.h>

#define NI 1024        // NUM_INPUTS
#define NH 1024        // NUM_HIDDEN
#define H4 4096        // 4*NUM_HIDDEN
#define FGB (-1.0f)
#define LN_EPS 1e-5f
#define NKT 32         // K/32 k-tiles

typedef unsigned short u16;
typedef __attribute__((ext_vector_type(8))) short short8;      // 8 bf16 (MFMA frag)
typedef __attribute__((ext_vector_type(8))) unsigned short ushort8v;
typedef __attribute__((ext_vector_type(16))) float f32x16;     // 32x32 accumulator

__device__ __forceinline__ float bf2f(u16 u) {
    union { unsigned int i; float f; } v; v.i = ((unsigned int)u) << 16; return v.f;
}
__device__ __forceinline__ u16 f2bf(float f) {
    __hip_bfloat16 h = __float2bfloat16(f);   // RNE
    return __builtin_bit_cast(u16, h);
}
__device__ __forceinline__ float fast_sigmoid(float x) {
    return 1.0f / (1.0f + __expf(-x));
}
__device__ __forceinline__ float fast_tanh(float x) {
    return 1.0f - 2.0f / (__expf(2.0f * x) + 1.0f);
}

// global (per-lane addr) -> LDS (wave-uniform base + lane*16B), async, width 16
__device__ __forceinline__ void gload16(const u16* g, u16* l) {
    __builtin_amdgcn_global_load_lds(
        (const __attribute__((address_space(1))) void*)g,
        (__attribute__((address_space(3))) void*)l,
        16, 0, 0);
}

// ---------------------------------------------------------------------------
// fp32 [4096 x 1024] -> bf16 in MFMA-fragment-linear order, via LDS transpose.
// chunk(mtile, kt, kh, lane) holds src[mtile*32 + (lane&31)][kt*32 + kh*16 + (lane>>5)*8 .. +8)
// stored at u16 offset ((mtile*NKT + kt)*2 + kh)*512 + lane*8.
// ---------------------------------------------------------------------------
__global__ __launch_bounds__(256) void shuffle_cast(
    const float* __restrict__ a, const float* __restrict__ b,
    const float* __restrict__ c, const float* __restrict__ d,
    u16* __restrict__ oa, u16* __restrict__ ob,
    u16* __restrict__ oc, u16* __restrict__ od)
{
    // row stride 264 u16 = 528 B: 16-B aligned rows (b128-safe), banks spread
    __shared__ u16 sT[32][264];

    const int my = blockIdx.y;
    const float* src = (my == 0) ? a : (my == 1) ? b : (my == 2) ? c : d;
    u16*         dst = (my == 0) ? oa : (my == 1) ? ob : (my == 2) ? oc : od;

    const int mtile = blockIdx.x >> 2;     // 0..127
    const int slab  = blockIdx.x & 3;      // 0..3 (256-col group = 8 k-tiles)
    const int t     = threadIdx.x;
    const int w     = t >> 6;              // wave 0..3
    const int lane  = t & 63;

    const float* s0 = src + (size_t)(mtile * 32) * 1024 + slab * 256 + lane * 4;
#pragma unroll
    for (int i = 0; i < 8; ++i) {
        const int row = i * 4 + w;                      // wave-uniform row
        float4 v = *(const float4*)(s0 + (size_t)row * 1024);
        ushort4 pk;
        pk.x = f2bf(v.x); pk.y = f2bf(v.y); pk.z = f2bf(v.z); pk.w = f2bf(v.w);
        *(ushort4*)&sT[row][lane * 4] = pk;
    }
    __syncthreads();

    const int r  = lane & 31;
    const int hi = lane >> 5;
#pragma unroll
    for (int j = 0; j < 2; ++j) {
        const int ktl = w * 2 + j;                      // 0..7 within slab
        const int kt  = slab * 8 + ktl;
        u16* o = dst + ((size_t)(mtile * 32 + kt)) * 1024 + lane * 8;
#pragma unroll
        for (int kh = 0; kh < 2; ++kh) {
            ushort8v vv = *(const ushort8v*)&sT[r][ktl * 32 + kh * 16 + hi * 8];
            *(ushort8v*)(o + kh * 512) = vv;
        }
    }
}

// ---------------------------------------------------------------------------
// C[M,N](bf16) = A @ W^T + bias, A/W pre-shuffled fragment-linear bf16.
// 256x256 block tile, FOUR waves (2Mx2N), 128x128 wave tile (4x4 of 32x32x16).
// Rationale (R3 post-mortem): at 8 waves the LDS read traffic (96 KB/kt) alone
// exceeds the MFMA wall (1033 cyc); halving read:MFMA ratio via a 2x bigger
// per-wave acc (256 AGPR) makes LDS non-binding (64+32 KB ~ 860 cyc < 1033).
// 1 wave/SIMD: overlap comes from within-wave pipelining (reads issued ahead,
// MFMA burst drains them underneath via compiler's counted lgkmcnt).
// LDS ring of 4 BK=32 slots (128 KB), staged depth-2 via global_load_lds,
// one barrier + counted vmcnt(8) per k-tile (never 0 in steady state).
// ---------------------------------------------------------------------------
__global__ __launch_bounds__(256, 1) void gemm_lds(
    const u16* __restrict__ Af0, const u16* __restrict__ Wf0,
    const float* __restrict__ bias0, u16* __restrict__ C0,
    const u16* __restrict__ Af1, const u16* __restrict__ Wf1,
    const float* __restrict__ bias1, u16* __restrict__ C1,
    int N)
{
    const u16*   Af   = blockIdx.z ? Af1 : Af0;
    const u16*   Wf   = blockIdx.z ? Wf1 : Wf0;
    const float* bias = blockIdx.z ? bias1 : bias0;
    u16*         C    = blockIdx.z ? C1 : C0;

    // [slot][mtile|ntile][kh][512 u16 fragment chunk] = 64 KB each, 128 KB total
    __shared__ __align__(16) u16 sA[4][8][2][512];
    __shared__ __align__(16) u16 sB[4][8][2][512];

    const int tid  = threadIdx.x;
    const int lane = tid & 63;
    const int wave = tid >> 6;         // 0..3
    const int wm   = wave >> 1;        // 0..1  (M half)
    const int wn   = wave & 1;         // 0..1  (N half)

    // staging: wave w owns A-mtiles {2w,2w+1} and B-ntiles {2w,2w+1}.
    // per-mtile stride = NKT*2*512 = 32768 u16; per-kt = 1024; per-kh = 512.
    const u16* gA0 = Af + (size_t)(blockIdx.y * 8 + wave * 2 + 0) * 32768 + lane * 8;
    const u16* gA1 = Af + (size_t)(blockIdx.y * 8 + wave * 2 + 1) * 32768 + lane * 8;
    const u16* gB0 = Wf + (size_t)(blockIdx.x * 8 + wave * 2 + 0) * 32768 + lane * 8;
    const u16* gB1 = Wf + (size_t)(blockIdx.x * 8 + wave * 2 + 1) * 32768 + lane * 8;

    f32x16 acc[4][4];
#pragma unroll
    for (int i = 0; i < 4; ++i)
#pragma unroll
        for (int j = 0; j < 4; ++j)
#pragma unroll
            for (int r = 0; r < 16; ++r)
                acc[i][j][r] = 0.f;

#define STAGE(kt)                                                             \
    do {                                                                      \
        gload16(gA0 + (size_t)(kt) * 1024,       &sA[(kt) & 3][wave * 2 + 0][0][0]); \
        gload16(gA0 + (size_t)(kt) * 1024 + 512, &sA[(kt) & 3][wave * 2 + 0][1][0]); \
        gload16(gA1 + (size_t)(kt) * 1024,       &sA[(kt) & 3][wave * 2 + 1][0][0]); \
        gload16(gA1 + (size_t)(kt) * 1024 + 512, &sA[(kt) & 3][wave * 2 + 1][1][0]); \
        gload16(gB0 + (size_t)(kt) * 1024,       &sB[(kt) & 3][wave * 2 + 0][0][0]); \
        gload16(gB0 + (size_t)(kt) * 1024 + 512, &sB[(kt) & 3][wave * 2 + 0][1][0]); \
        gload16(gB1 + (size_t)(kt) * 1024,       &sB[(kt) & 3][wave * 2 + 1][0][0]); \
        gload16(gB1 + (size_t)(kt) * 1024 + 512, &sB[(kt) & 3][wave * 2 + 1][1][0]); \
    } while (0)

    // two fragment register sets: set0 = kh0 of current tile, set1 = kh1
    ushort8v a0_0, a1_0, a2_0, a3_0, b0_0, b1_0, b2_0, b3_0;   // set0
    ushort8v a0_1, a1_1, a2_1, a3_1, b0_1, b1_1, b2_1, b3_1;   // set1

#define R0(slot)                                                             \
    do {                                                                     \
        a0_0 = *(const ushort8v*)&sA[slot][wm * 4 + 0][0][lane * 8];         \
        b0_0 = *(const ushort8v*)&sB[slot][wn * 4 + 0][0][lane * 8];         \
        a1_0 = *(const ushort8v*)&sA[slot][wm * 4 + 1][0][lane * 8];         \
        b1_0 = *(const ushort8v*)&sB[slot][wn * 4 + 1][0][lane * 8];         \
        a2_0 = *(const ushort8v*)&sA[slot][wm * 4 + 2][0][lane * 8];         \
        b2_0 = *(const ushort8v*)&sB[slot][wn * 4 + 2][0][lane * 8];         \
        a3_0 = *(const ushort8v*)&sA[slot][wm * 4 + 3][0][lane * 8];         \
        b3_0 = *(const ushort8v*)&sB[slot][wn * 4 + 3][0][lane * 8];         \
    } while (0)
#define R1(slot)                                                             \
    do {                                                                     \
        a0_1 = *(const ushort8v*)&sA[slot][wm * 4 + 0][1][lane * 8];         \
        b0_1 = *(const ushort8v*)&sB[slot][wn * 4 + 0][1][lane * 8];         \
        a1_1 = *(const ushort8v*)&sA[slot][wm * 4 + 1][1][lane * 8];         \
        b1_1 = *(const ushort8v*)&sB[slot][wn * 4 + 1][1][lane * 8];         \
        a2_1 = *(const ushort8v*)&sA[slot][wm * 4 + 2][1][lane * 8];         \
        b2_1 = *(const ushort8v*)&sB[slot][wn * 4 + 2][1][lane * 8];         \
        a3_1 = *(const ushort8v*)&sA[slot][wm * 4 + 3][1][lane * 8];         \
        b3_1 = *(const ushort8v*)&sB[slot][wn * 4 + 3][1][lane * 8];         \
    } while (0)

#define MM(i, j, aa, bb) \
    acc[i][j] = __builtin_amdgcn_mfma_f32_32x32x16_bf16((short8)aa, (short8)bb, acc[i][j], 0, 0, 0)

    // 16 MFMAs of one kh: 4x4 acc grid, all independent chains
#define M16(s)                                                               \
    do {                                                                     \
        __builtin_amdgcn_s_setprio(1);                                       \
        MM(0, 0, a0_##s, b0_##s); MM(1, 0, a1_##s, b0_##s);                  \
        MM(0, 1, a0_##s, b1_##s); MM(1, 1, a1_##s, b1_##s);                  \
        MM(2, 0, a2_##s, b0_##s); MM(3, 0, a3_##s, b0_##s);                  \
        MM(2, 1, a2_##s, b1_##s); MM(3, 1, a3_##s, b1_##s);                  \
        MM(0, 2, a0_##s, b2_##s); MM(1, 2, a1_##s, b2_##s);                  \
        MM(0, 3, a0_##s, b3_##s); MM(1, 3, a1_##s, b3_##s);                  \
        MM(2, 2, a2_##s, b2_##s); MM(3, 2, a3_##s, b2_##s);                  \
        MM(2, 3, a2_##s, b3_##s); MM(3, 3, a3_##s, b3_##s);                  \
        __builtin_amdgcn_s_setprio(0);                                       \
    } while (0)

#define FENCE() asm volatile("" ::: "memory")

    // ---- prologue: stage tiles 0,1 (16 loads); wait tile 0; stage tile 2 ----
    STAGE(0);
    STAGE(1);
    asm volatile("s_waitcnt vmcnt(8)" ::: "memory");
    FENCE();
    __builtin_amdgcn_s_barrier();
    FENCE();
    STAGE(2);
    R0(0);
    R1(0);
    M16(0);                          // tile 0, kh0   (kh1 deferred)

    // ---- steady loop: on entry set1 holds tile kt-1 kh1 (MFMAs pending) ----
#pragma unroll
    for (int kt = 1; kt < NKT; ++kt) {
        const int slot = kt & 3;
        if (kt == NKT - 1) {
            asm volatile("s_waitcnt vmcnt(0)" ::: "memory");
        } else {
            asm volatile("s_waitcnt vmcnt(8)" ::: "memory");
        }
        FENCE();
        __builtin_amdgcn_s_barrier();
        FENCE();
        if (kt + 2 < NKT) STAGE(kt + 2);
        R0(slot);                    // 8 ds_read -> set0 (tile kt, kh0)
        M16(1);                      // tile kt-1, kh1  [covers R0 drain]
        R1(slot);                    // 8 ds_read -> set1 (tile kt, kh1)
        M16(0);                      // tile kt, kh0    [covers R1 drain]
    }
    M16(1);                          // tile NKT-1, kh1

#undef STAGE
#undef R0
#undef R1
#undef MM
#undef M16
#undef FENCE

    // epilogue: C/D layout col = lane&31, row = (reg&3) + 8*(reg>>2) + 4*(lane>>5)
    const int m0  = blockIdx.y * 256;
    const int n0  = blockIdx.x * 256;
    const int l31 = lane & 31;
    float bv[4];
#pragma unroll
    for (int tn = 0; tn < 4; ++tn)
        bv[tn] = bias[n0 + wn * 128 + tn * 32 + l31];

    const int rbase = (lane >> 5) * 4;
#pragma unroll
    for (int tm = 0; tm < 4; ++tm)
#pragma unroll
        for (int reg = 0; reg < 16; ++reg) {
            const int row = m0 + wm * 128 + tm * 32 + (reg & 3) + 8 * (reg >> 2) + rbase;
#pragma unroll
            for (int tn = 0; tn < 4; ++tn) {
                const int col = n0 + wn * 128 + tn * 32 + l31;
                C[(size_t)row * N + col] = f2bf(acc[tm][tn][reg] + bv[tn]);
            }
        }
}

// ---------------------------------------------------------------------------
// Pointwise: block-per-row, single HBM pass, bf16 LDS staging (16 KB).
// ---------------------------------------------------------------------------
__global__ __launch_bounds__(256) void lstm_pointwise(
    const u16* __restrict__ i2h, const u16* __restrict__ h2h,
    const float* __restrict__ cx,
    const float* __restrict__ lwx, const float* __restrict__ lbx,
    const float* __restrict__ lwy, const float* __restrict__ lby,
    const float* __restrict__ lwc, const float* __restrict__ lbc,
    float* __restrict__ hx_out, float* __restrict__ cx_out)
{
    __shared__ u16 sX[H4];
    __shared__ u16 sY[H4];
    __shared__ float red[16];

    const int row  = blockIdx.x;
    const int tid  = threadIdx.x;
    const int lane = tid & 63;
    const int wid  = tid >> 6;

    const u16* xr = i2h + (size_t)row * H4;
    const u16* yr = h2h + (size_t)row * H4;

    float sx = 0.f, sxx = 0.f, sy = 0.f, syy = 0.f;
#pragma unroll
    for (int s = 0; s < 2; ++s) {
        const int off = s * 2048 + tid * 8;
        ushort8v xv = *(const ushort8v*)(xr + off);
        ushort8v yv = *(const ushort8v*)(yr + off);
        *(ushort8v*)(sX + off) = xv;
        *(ushort8v*)(sY + off) = yv;
#pragma unroll
        for (int e = 0; e < 8; ++e) {
            float x = bf2f(xv[e]), y = bf2f(yv[e]);
            sx += x; sxx += x * x; sy += y; syy += y * y;
        }
    }
#pragma unroll
    for (int m = 32; m; m >>= 1) {
        sx  += __shfl_xor(sx,  m, 64);
        sxx += __shfl_xor(sxx, m, 64);
        sy  += __shfl_xor(sy,  m, 64);
        syy += __shfl_xor(syy, m, 64);
    }
    if (lane == 0) {
        red[wid] = sx; red[4 + wid] = sxx; red[8 + wid] = sy; red[12 + wid] = syy;
    }
    __syncthreads();
    const float tsx  = red[0] + red[1] + red[2] + red[3];
    const float tsxx = red[4] + red[5] + red[6] + red[7];
    const float tsy  = red[8] + red[9] + red[10] + red[11];
    const float tsyy = red[12] + red[13] + red[14] + red[15];
    __syncthreads();

    const float n1  = (float)H4;
    const float mx  = tsx / n1;
    const float ivx = 1.0f / (sqrtf(fmaxf((tsxx - tsx * tsx / n1) / (n1 - 1.f), 0.f)) + LN_EPS);
    const float my  = tsy / n1;
    const float ivy = 1.0f / (sqrtf(fmaxf((tsyy - tsy * tsy / n1) / (n1 - 1.f), 0.f)) + LN_EPS);

    const int j0 = tid * 4;
    float gate[4][4];
#pragma unroll
    for (int g = 0; g < 4; ++g) {
        ushort4 xv = *(const ushort4*)(sX + g * NH + j0);
        ushort4 yv = *(const ushort4*)(sY + g * NH + j0);
        float4 wxv = *(const float4*)(lwx + g * NH + j0);
        float4 bxv = *(const float4*)(lbx + g * NH + j0);
        float4 wyv = *(const float4*)(lwy + g * NH + j0);
        float4 byv = *(const float4*)(lby + g * NH + j0);
        gate[g][0] = (bf2f(xv.x) - mx) * ivx * wxv.x + bxv.x + (bf2f(yv.x) - my) * ivy * wyv.x + byv.x;
        gate[g][1] = (bf2f(xv.y) - mx) * ivx * wxv.y + bxv.y + (bf2f(yv.y) - my) * ivy * wyv.y + byv.y;
        gate[g][2] = (bf2f(xv.z) - mx) * ivx * wxv.z + bxv.z + (bf2f(yv.z) - my) * ivy * wyv.z + byv.z;
        gate[g][3] = (bf2f(xv.w) - mx) * ivx * wxv.w + bxv.w + (bf2f(yv.w) - my) * ivy * wyv.w + byv.w;
    }

    float4 cxv = *(const float4*)(cx + (size_t)row * NH + j0);
    const float cin[4] = {cxv.x, cxv.y, cxv.z, cxv.w};
    float cvl[4], og[4];
    float sc = 0.f, scc = 0.f;
#pragma unroll
    for (int e = 0; e < 4; ++e) {
        float ing = fast_sigmoid(gate[0][e]);
        float fg  = fast_sigmoid(gate[1][e] + FGB);
        og[e]     = fast_sigmoid(gate[2][e]);
        float tr  = fast_tanh(gate[3][e]);
        float c   = fg * cin[e] + ing * tr;
        cvl[e] = c; sc += c; scc += c * c;
    }
    *(float4*)(cx_out + (size_t)row * NH + j0) = make_float4(cvl[0], cvl[1], cvl[2], cvl[3]);

#pragma unroll
    for (int m = 32; m; m >>= 1) {
        sc  += __shfl_xor(sc,  m, 64);
        scc += __shfl_xor(scc, m, 64);
    }
    if (lane == 0) { red[wid] = sc; red[4 + wid] = scc; }
    __syncthreads();
    const float tsc  = red[0] + red[1] + red[2] + red[3];
    const float tscc = red[4] + red[5] + red[6] + red[7];

    const float nc  = (float)NH;
    const float mc  = tsc / nc;
    const float ivc = 1.0f / (sqrtf(fmaxf((tscc - tsc * tsc / nc) / (nc - 1.f), 0.f)) + LN_EPS);

    float4 wcv = *(const float4*)(lwc + j0);
    float4 bcv = *(const float4*)(lbc + j0);
    float h0 = og[0] * fast_tanh((cvl[0] - mc) * ivc * wcv.x + bcv.x);
    float h1 = og[1] * fast_tanh((cvl[1] - mc) * ivc * wcv.y + bcv.y);
    float h2 = og[2] * fast_tanh((cvl[2] - mc) * ivc * wcv.z + bcv.z);
    float h3 = og[3] * fast_tanh((cvl[3] - mc) * ivc * wcv.w + bcv.w);
    *(float4*)(hx_out + (size_t)row * NH + j0) = make_float4(h0, h1, h2, h3);
}

// ---------------------------------------------------------------------------
extern "C" void kernel_launch(void* const* d_in, const int* in_sizes, int n_in,
                              void* d_out, int out_size, void* d_ws, size_t ws_size,
                              hipStream_t stream) {
    const float* inputs = (const float*)d_in[0];
    const float* hx     = (const float*)d_in[1];
    const float* cx     = (const float*)d_in[2];
    const float* w_i2h  = (const float*)d_in[3];
    const float* b_i2h  = (const float*)d_in[4];
    const float* w_h2h  = (const float*)d_in[5];
    const float* b_h2h  = (const float*)d_in[6];
    const float* lwx    = (const float*)d_in[7];
    const float* lbx    = (const float*)d_in[8];
    const float* lwy    = (const float*)d_in[9];
    const float* lby    = (const float*)d_in[10];
    const float* lwc    = (const float*)d_in[11];
    const float* lbc    = (const float*)d_in[12];

    const int B = in_sizes[0] / NI;                // 4096

    u16* a_fr   = (u16*)d_ws;                      // fragment-linear, 8 MB each
    u16* hx_fr  = a_fr   + (size_t)B * NI;
    u16* wi_fr  = hx_fr  + (size_t)B * NH;
    u16* wh_fr  = wi_fr  + (size_t)H4 * NI;
    u16* i2h_bf = wh_fr  + (size_t)H4 * NH;        // row-major outputs, 32 MB each
    u16* h2h_bf = i2h_bf + (size_t)B * H4;

    float* hx_out = (float*)d_out;
    float* cx_out = hx_out + (size_t)B * NH;

    // 128 mtiles x 4 slabs = 512 blocks per matrix
    shuffle_cast<<<dim3(512, 4), dim3(256), 0, stream>>>(
        inputs, hx, w_i2h, w_h2h, a_fr, hx_fr, wi_fr, wh_fr);

    gemm_lds<<<dim3(H4 / 256, B / 256, 2), dim3(256), 0, stream>>>(
        a_fr, wi_fr, b_i2h, i2h_bf,
        hx_fr, wh_fr, b_h2h, h2h_bf,
        H4);

    lstm_pointwise<<<dim3(B), dim3(256), 0, stream>>>(
        i2h_bf, h2h_bf, cx, lwx, lbx, lwy, lby, lwc, lbc, hx_out, cx_out);
}

// Round 6
// 237.633 us; speedup vs baseline: 1.0549x; 1.0549x over previous
//
#include <hip/hip_runtime.h>
#include <hip/hip_bf16.h>
#include <math.h>

#define NI 1024        // NUM_INPUTS
#define NH 1024        // NUM_HIDDEN
#define H4 4096        // 4*NUM_HIDDEN
#define FGB (-1.0f)
#define LN_EPS 1e-5f
#define NKT 32         // K/32 k-tiles

typedef unsigned short u16;
typedef __attribute__((ext_vector_type(8))) short short8;      // 8 bf16 (MFMA frag)
typedef __attribute__((ext_vector_type(8))) unsigned short ushort8v;
typedef __attribute__((ext_vector_type(16))) float f32x16;     // 32x32 accumulator

__device__ __forceinline__ float bf2f(u16 u) {
    union { unsigned int i; float f; } v; v.i = ((unsigned int)u) << 16; return v.f;
}
__device__ __forceinline__ u16 f2bf(float f) {
    __hip_bfloat16 h = __float2bfloat16(f);   // RNE
    return __builtin_bit_cast(u16, h);
}
__device__ __forceinline__ float fast_sigmoid(float x) {
    return 1.0f / (1.0f + __expf(-x));
}
__device__ __forceinline__ float fast_tanh(float x) {
    return 1.0f - 2.0f / (__expf(2.0f * x) + 1.0f);
}

// global (per-lane addr) -> LDS (wave-uniform base + lane*16B), async, width 16
__device__ __forceinline__ void gload16(const u16* g, u16* l) {
    __builtin_amdgcn_global_load_lds(
        (const __attribute__((address_space(1))) void*)g,
        (__attribute__((address_space(3))) void*)l,
        16, 0, 0);
}

// ---------------------------------------------------------------------------
// fp32 [4096 x 1024] -> bf16 in MFMA-fragment-linear order, via LDS transpose.
// chunk(mtile, kt, kh, lane) holds src[mtile*32 + (lane&31)][kt*32 + kh*16 + (lane>>5)*8 .. +8)
// stored at u16 offset ((mtile*NKT + kt)*2 + kh)*512 + lane*8.
// ---------------------------------------------------------------------------
__global__ __launch_bounds__(256) void shuffle_cast(
    const float* __restrict__ a, const float* __restrict__ b,
    const float* __restrict__ c, const float* __restrict__ d,
    u16* __restrict__ oa, u16* __restrict__ ob,
    u16* __restrict__ oc, u16* __restrict__ od)
{
    // row stride 264 u16 = 528 B: 16-B aligned rows (b128-safe), banks spread
    __shared__ u16 sT[32][264];

    const int my = blockIdx.y;
    const float* src = (my == 0) ? a : (my == 1) ? b : (my == 2) ? c : d;
    u16*         dst = (my == 0) ? oa : (my == 1) ? ob : (my == 2) ? oc : od;

    const int mtile = blockIdx.x >> 2;     // 0..127
    const int slab  = blockIdx.x & 3;      // 0..3 (256-col group = 8 k-tiles)
    const int t     = threadIdx.x;
    const int w     = t >> 6;              // wave 0..3
    const int lane  = t & 63;

    const float* s0 = src + (size_t)(mtile * 32) * 1024 + slab * 256 + lane * 4;
#pragma unroll
    for (int i = 0; i < 8; ++i) {
        const int row = i * 4 + w;                      // wave-uniform row
        float4 v = *(const float4*)(s0 + (size_t)row * 1024);
        ushort4 pk;
        pk.x = f2bf(v.x); pk.y = f2bf(v.y); pk.z = f2bf(v.z); pk.w = f2bf(v.w);
        *(ushort4*)&sT[row][lane * 4] = pk;
    }
    __syncthreads();

    const int r  = lane & 31;
    const int hi = lane >> 5;
#pragma unroll
    for (int j = 0; j < 2; ++j) {
        const int ktl = w * 2 + j;                      // 0..7 within slab
        const int kt  = slab * 8 + ktl;
        u16* o = dst + ((size_t)(mtile * 32 + kt)) * 1024 + lane * 8;
#pragma unroll
        for (int kh = 0; kh < 2; ++kh) {
            ushort8v vv = *(const ushort8v*)&sT[r][ktl * 32 + kh * 16 + hi * 8];
            *(ushort8v*)(o + kh * 512) = vv;
        }
    }
}

// ---------------------------------------------------------------------------
// C[M,N](bf16) = A @ W^T + bias, A/W pre-shuffled fragment-linear bf16.
// 256x256 block tile, 8 waves (2Mx4N), 128x64 wave tile (4x2 of 32x32x16).
// LDS ring of 4 BK=32 slots (128 KB), staged depth-2 via global_load_lds,
// one barrier + counted vmcnt(4) per k-tile (never 0 in steady state).
// R6: ANTI-PHASE wave scheduling. R1-R3 evidence: all-lockstep phases
// serialize the LDS-read burst (96 KB/kt ~ 1150 cyc) and the MFMA burst
// (1033 cyc) -> wall ~ sum (MfmaUtil 37%). Odd waves run a mirrored window
// order {MFMA(prev); reads; MFMA(cur)} vs even {reads; MFMA(prev); reads;
// MFMA(cur)}, pinned with sched_barrier(0), so the LDS unit serves one
// parity group while the other issues MFMAs -> the two pipes overlap.
// ---------------------------------------------------------------------------
__global__ __launch_bounds__(512, 2) void gemm_lds(
    const u16* __restrict__ Af0, const u16* __restrict__ Wf0,
    const float* __restrict__ bias0, u16* __restrict__ C0,
    const u16* __restrict__ Af1, const u16* __restrict__ Wf1,
    const float* __restrict__ bias1, u16* __restrict__ C1,
    int N)
{
    const u16*   Af   = blockIdx.z ? Af1 : Af0;
    const u16*   Wf   = blockIdx.z ? Wf1 : Wf0;
    const float* bias = blockIdx.z ? bias1 : bias0;
    u16*         C    = blockIdx.z ? C1 : C0;

    // [slot][mtile|ntile][kh][512 u16 fragment chunk] = 64 KB each, 128 KB total
    __shared__ __align__(16) u16 sA[4][8][2][512];
    __shared__ __align__(16) u16 sB[4][8][2][512];

    const int tid  = threadIdx.x;
    const int lane = tid & 63;
    const int wave = tid >> 6;         // 0..7
    const int wm   = wave >> 2;        // 0..1  (M half)
    const int wn   = wave & 3;         // 0..3  (N quarter)

    // staging: wave w owns A-mtile (by*8+w) and B-ntile (bx*8+w).
    // per-mtile stride = NKT*2*512 = 32768 u16; per-kt = 1024; per-kh = 512.
    const u16* gA = Af + (size_t)(blockIdx.y * 8 + wave) * 32768 + lane * 8;
    const u16* gB = Wf + (size_t)(blockIdx.x * 8 + wave) * 32768 + lane * 8;

    f32x16 acc[4][2];
#pragma unroll
    for (int i = 0; i < 4; ++i)
#pragma unroll
        for (int j = 0; j < 2; ++j)
#pragma unroll
            for (int r = 0; r < 16; ++r)
                acc[i][j][r] = 0.f;

#define STAGE(kt)                                                            \
    do {                                                                     \
        gload16(gA + (size_t)(kt) * 1024,       &sA[(kt) & 3][wave][0][0]);  \
        gload16(gA + (size_t)(kt) * 1024 + 512, &sA[(kt) & 3][wave][1][0]);  \
        gload16(gB + (size_t)(kt) * 1024,       &sB[(kt) & 3][wave][0][0]);  \
        gload16(gB + (size_t)(kt) * 1024 + 512, &sB[(kt) & 3][wave][1][0]);  \
    } while (0)

    // two fragment register sets: set0 = kh0 of current tile, set1 = kh1
    ushort8v a0_0, a1_0, a2_0, a3_0, b0_0, b1_0;   // set0
    ushort8v a0_1, a1_1, a2_1, a3_1, b0_1, b1_1;   // set1

#define R0(slot)                                                             \
    do {                                                                     \
        a0_0 = *(const ushort8v*)&sA[slot][wm * 4 + 0][0][lane * 8];         \
        b0_0 = *(const ushort8v*)&sB[slot][wn * 2 + 0][0][lane * 8];         \
        a1_0 = *(const ushort8v*)&sA[slot][wm * 4 + 1][0][lane * 8];         \
        b1_0 = *(const ushort8v*)&sB[slot][wn * 2 + 1][0][lane * 8];         \
        a2_0 = *(const ushort8v*)&sA[slot][wm * 4 + 2][0][lane * 8];         \
        a3_0 = *(const ushort8v*)&sA[slot][wm * 4 + 3][0][lane * 8];         \
    } while (0)
#define R1(slot)                                                             \
    do {                                                                     \
        a0_1 = *(const ushort8v*)&sA[slot][wm * 4 + 0][1][lane * 8];         \
        b0_1 = *(const ushort8v*)&sB[slot][wn * 2 + 0][1][lane * 8];         \
        a1_1 = *(const ushort8v*)&sA[slot][wm * 4 + 1][1][lane * 8];         \
        b1_1 = *(const ushort8v*)&sB[slot][wn * 2 + 1][1][lane * 8];         \
        a2_1 = *(const ushort8v*)&sA[slot][wm * 4 + 2][1][lane * 8];         \
        a3_1 = *(const ushort8v*)&sA[slot][wm * 4 + 3][1][lane * 8];         \
    } while (0)

#define MM(i, j, aa, bb) \
    acc[i][j] = __builtin_amdgcn_mfma_f32_32x32x16_bf16((short8)aa, (short8)bb, acc[i][j], 0, 0, 0)

#define M8(s)                                                                \
    do {                                                                     \
        __builtin_amdgcn_s_setprio(1);                                       \
        MM(0, 0, a0_##s, b0_##s); MM(1, 0, a1_##s, b0_##s);                  \
        MM(0, 1, a0_##s, b1_##s); MM(1, 1, a1_##s, b1_##s);                  \
        MM(2, 0, a2_##s, b0_##s); MM(3, 0, a3_##s, b0_##s);                  \
        MM(2, 1, a2_##s, b1_##s); MM(3, 1, a3_##s, b1_##s);                  \
        __builtin_amdgcn_s_setprio(0);                                       \
    } while (0)

#define FENCE() asm volatile("" ::: "memory")
#define WIN_TOP(kt)                                                          \
    do {                                                                     \
        if ((kt) == NKT - 1) {                                               \
            asm volatile("s_waitcnt vmcnt(0)" ::: "memory");                 \
        } else {                                                             \
            asm volatile("s_waitcnt vmcnt(4)" ::: "memory");                 \
        }                                                                    \
        FENCE();                                                             \
        __builtin_amdgcn_s_barrier();                                        \
        FENCE();                                                             \
        if ((kt) + 2 < NKT) STAGE((kt) + 2);                                 \
    } while (0)

    // ---- prologue (both parities): stage 0,1; wait tile 0; stage 2 ----
    STAGE(0);
    STAGE(1);
    asm volatile("s_waitcnt vmcnt(4)" ::: "memory");
    FENCE();
    __builtin_amdgcn_s_barrier();
    FENCE();
    STAGE(2);
    R0(0);
    R1(0);
    M8(0);                           // tile 0, kh0   (kh1 deferred in set1)

    if ((wave & 1) == 0) {
        // EVEN waves: reads-first window (R3 order)
#pragma unroll
        for (int kt = 1; kt < NKT; ++kt) {
            const int slot = kt & 3;
            WIN_TOP(kt);
            R0(slot);                // 6 ds_read -> set0 (tile kt, kh0)
            M8(1);                   // tile kt-1, kh1
            R1(slot);                // 6 ds_read -> set1 (tile kt, kh1)
            M8(0);                   // tile kt,   kh0
        }
    } else {
        // ODD waves: MFMA-first window (anti-phase); sched_barrier pins the
        // MFMA cluster ahead of the reads so the compiler can't hoist loads.
#pragma unroll
        for (int kt = 1; kt < NKT; ++kt) {
            const int slot = kt & 3;
            WIN_TOP(kt);
            M8(1);                   // tile kt-1, kh1  [overlaps even waves' reads]
            __builtin_amdgcn_sched_barrier(0);
            R0(slot);                // 12 ds_read back-to-back
            R1(slot);
            M8(0);                   // tile kt, kh0 (covers R1 drain)
        }
    }
    M8(1);                           // tile NKT-1, kh1

#undef STAGE
#undef R0
#undef R1
#undef MM
#undef M8
#undef WIN_TOP
#undef FENCE

    // epilogue: C/D layout col = lane&31, row = (reg&3) + 8*(reg>>2) + 4*(lane>>5)
    const int m0  = blockIdx.y * 256;
    const int n0  = blockIdx.x * 256;
    const int l31 = lane & 31;
    float bv[2];
#pragma unroll
    for (int tn = 0; tn < 2; ++tn)
        bv[tn] = bias[n0 + wn * 64 + tn * 32 + l31];

    const int rbase = (lane >> 5) * 4;
#pragma unroll
    for (int tm = 0; tm < 4; ++tm)
#pragma unroll
        for (int reg = 0; reg < 16; ++reg) {
            const int row = m0 + wm * 128 + tm * 32 + (reg & 3) + 8 * (reg >> 2) + rbase;
#pragma unroll
            for (int tn = 0; tn < 2; ++tn) {
                const int col = n0 + wn * 64 + tn * 32 + l31;
                C[(size_t)row * N + col] = f2bf(acc[tm][tn][reg] + bv[tn]);
            }
        }
}

// ---------------------------------------------------------------------------
// Pointwise: block-per-row, fully register-resident (no LDS staging).
// Each thread owns elements [g*1024 + tid*4 .. +3] of all 4 gate quarters
// for both i2h and h2h: loads are coalesced 512B/wave segments, and the
// gate phase reads registers instead of LDS.
// ---------------------------------------------------------------------------
__global__ __launch_bounds__(256) void lstm_pointwise(
    const u16* __restrict__ i2h, const u16* __restrict__ h2h,
    const float* __restrict__ cx,
    const float* __restrict__ lwx, const float* __restrict__ lbx,
    const float* __restrict__ lwy, const float* __restrict__ lby,
    const float* __restrict__ lwc, const float* __restrict__ lbc,
    float* __restrict__ hx_out, float* __restrict__ cx_out)
{
    __shared__ float red[16];

    const int row  = blockIdx.x;
    const int tid  = threadIdx.x;
    const int lane = tid & 63;
    const int wid  = tid >> 6;
    const int j0   = tid * 4;

    const u16* xr = i2h + (size_t)row * H4;
    const u16* yr = h2h + (size_t)row * H4;

    float xf[4][4], yf[4][4];
    float sx = 0.f, sxx = 0.f, sy = 0.f, syy = 0.f;
#pragma unroll
    for (int g = 0; g < 4; ++g) {
        ushort4 xv = *(const ushort4*)(xr + g * NH + j0);
        ushort4 yv = *(const ushort4*)(yr + g * NH + j0);
        xf[g][0] = bf2f(xv.x); xf[g][1] = bf2f(xv.y);
        xf[g][2] = bf2f(xv.z); xf[g][3] = bf2f(xv.w);
        yf[g][0] = bf2f(yv.x); yf[g][1] = bf2f(yv.y);
        yf[g][2] = bf2f(yv.z); yf[g][3] = bf2f(yv.w);
#pragma unroll
        for (int e = 0; e < 4; ++e) {
            sx += xf[g][e]; sxx += xf[g][e] * xf[g][e];
            sy += yf[g][e]; syy += yf[g][e] * yf[g][e];
        }
    }
#pragma unroll
    for (int m = 32; m; m >>= 1) {
        sx  += __shfl_xor(sx,  m, 64);
        sxx += __shfl_xor(sxx, m, 64);
        sy  += __shfl_xor(sy,  m, 64);
        syy += __shfl_xor(syy, m, 64);
    }
    if (lane == 0) {
        red[wid] = sx; red[4 + wid] = sxx; red[8 + wid] = sy; red[12 + wid] = syy;
    }
    __syncthreads();
    const float tsx  = red[0] + red[1] + red[2] + red[3];
    const float tsxx = red[4] + red[5] + red[6] + red[7];
    const float tsy  = red[8] + red[9] + red[10] + red[11];
    const float tsyy = red[12] + red[13] + red[14] + red[15];

    const float n1  = (float)H4;
    const float mx  = tsx / n1;
    const float ivx = 1.0f / (sqrtf(fmaxf((tsxx - tsx * tsx / n1) / (n1 - 1.f), 0.f)) + LN_EPS);
    const float my  = tsy / n1;
    const float ivy = 1.0f / (sqrtf(fmaxf((tsyy - tsy * tsy / n1) / (n1 - 1.f), 0.f)) + LN_EPS);

    float gate[4][4];
#pragma unroll
    for (int g = 0; g < 4; ++g) {
        float4 wxv = *(const float4*)(lwx + g * NH + j0);
        float4 bxv = *(const float4*)(lbx + g * NH + j0);
        float4 wyv = *(const float4*)(lwy + g * NH + j0);
        float4 byv = *(const float4*)(lby + g * NH + j0);
        gate[g][0] = (xf[g][0] - mx) * ivx * wxv.x + bxv.x + (yf[g][0] - my) * ivy * wyv.x + byv.x;
        gate[g][1] = (xf[g][1] - mx) * ivx * wxv.y + bxv.y + (yf[g][1] - my) * ivy * wyv.y + byv.y;
        gate[g][2] = (xf[g][2] - mx) * ivx * wxv.z + bxv.z + (yf[g][2] - my) * ivy * wyv.z + byv.z;
        gate[g][3] = (xf[g][3] - mx) * ivx * wxv.w + bxv.w + (yf[g][3] - my) * ivy * wyv.w + byv.w;
    }

    float4 cxv = *(const float4*)(cx + (size_t)row * NH + j0);
    const float cin[4] = {cxv.x, cxv.y, cxv.z, cxv.w};
    float cvl[4], og[4];
    float sc = 0.f, scc = 0.f;
#pragma unroll
    for (int e = 0; e < 4; ++e) {
        float ing = fast_sigmoid(gate[0][e]);
        float fg  = fast_sigmoid(gate[1][e] + FGB);
        og[e]     = fast_sigmoid(gate[2][e]);
        float tr  = fast_tanh(gate[3][e]);
        float c   = fg * cin[e] + ing * tr;
        cvl[e] = c; sc += c; scc += c * c;
    }
    *(float4*)(cx_out + (size_t)row * NH + j0) = make_float4(cvl[0], cvl[1], cvl[2], cvl[3]);

#pragma unroll
    for (int m = 32; m; m >>= 1) {
        sc  += __shfl_xor(sc,  m, 64);
        scc += __shfl_xor(scc, m, 64);
    }
    __syncthreads();   // red[] reuse
    if (lane == 0) { red[wid] = sc; red[4 + wid] = scc; }
    __syncthreads();
    const float tsc  = red[0] + red[1] + red[2] + red[3];
    const float tscc = red[4] + red[5] + red[6] + red[7];

    const float nc  = (float)NH;
    const float mc  = tsc / nc;
    const float ivc = 1.0f / (sqrtf(fmaxf((tscc - tsc * tsc / nc) / (nc - 1.f), 0.f)) + LN_EPS);

    float4 wcv = *(const float4*)(lwc + j0);
    float4 bcv = *(const float4*)(lbc + j0);
    float h0 = og[0] * fast_tanh((cvl[0] - mc) * ivc * wcv.x + bcv.x);
    float h1 = og[1] * fast_tanh((cvl[1] - mc) * ivc * wcv.y + bcv.y);
    float h2 = og[2] * fast_tanh((cvl[2] - mc) * ivc * wcv.z + bcv.z);
    float h3 = og[3] * fast_tanh((cvl[3] - mc) * ivc * wcv.w + bcv.w);
    *(float4*)(hx_out + (size_t)row * NH + j0) = make_float4(h0, h1, h2, h3);
}

// ---------------------------------------------------------------------------
extern "C" void kernel_launch(void* const* d_in, const int* in_sizes, int n_in,
                              void* d_out, int out_size, void* d_ws, size_t ws_size,
                              hipStream_t stream) {
    const float* inputs = (const float*)d_in[0];
    const float* hx     = (const float*)d_in[1];
    const float* cx     = (const float*)d_in[2];
    const float* w_i2h  = (const float*)d_in[3];
    const float* b_i2h  = (const float*)d_in[4];
    const float* w_h2h  = (const float*)d_in[5];
    const float* b_h2h  = (const float*)d_in[6];
    const float* lwx    = (const float*)d_in[7];
    const float* lbx    = (const float*)d_in[8];
    const float* lwy    = (const float*)d_in[9];
    const float* lby    = (const float*)d_in[10];
    const float* lwc    = (const float*)d_in[11];
    const float* lbc    = (const float*)d_in[12];

    const int B = in_sizes[0] / NI;                // 4096

    u16* a_fr   = (u16*)d_ws;                      // fragment-linear, 8 MB each
    u16* hx_fr  = a_fr   + (size_t)B * NI;
    u16* wi_fr  = hx_fr  + (size_t)B * NH;
    u16* wh_fr  = wi_fr  + (size_t)H4 * NI;
    u16* i2h_bf = wh_fr  + (size_t)H4 * NH;        // row-major outputs, 32 MB each
    u16* h2h_bf = i2h_bf + (size_t)B * H4;

    float* hx_out = (float*)d_out;
    float* cx_out = hx_out + (size_t)B * NH;

    // 128 mtiles x 4 slabs = 512 blocks per matrix
    shuffle_cast<<<dim3(512, 4), dim3(256), 0, stream>>>(
        inputs, hx, w_i2h, w_h2h, a_fr, hx_fr, wi_fr, wh_fr);

    gemm_lds<<<dim3(H4 / 256, B / 256, 2), dim3(512), 0, stream>>>(
        a_fr, wi_fr, b_i2h, i2h_bf,
        hx_fr, wh_fr, b_h2h, h2h_bf,
        H4);

    lstm_pointwise<<<dim3(B), dim3(256), 0, stream>>>(
        i2h_bf, h2h_bf, cx, lwx, lbx, lwy, lby, lwc, lbc, hx_out, cx_out);
}